// Round 14
// baseline (98.976 us; speedup 1.0000x reference)
//
#include <hip/hip_runtime.h>
#include <math.h>

typedef short short8 __attribute__((ext_vector_type(8)));
typedef float f32x4  __attribute__((ext_vector_type(4)));

constexpr int Ssz = 512, Dsz = 64, Lsz = 4, Bsz = 32;
constexpr int TI = 32, TJ = 64;

// LDS: X^T double-buffered [2][64 d][64 j] bf16, 16B-granule XOR swizzle (g ^= d&7).
constexpr int XTb[2] = {0, 4096};                 // short offsets
// epilogue overlay (floats; X buffers dead by then)
constexpr int YBs = 69;                           // 69 == 5 mod 32 -> conflict-free
constexpr int YB_f = 0;                           // [32][69]
constexpr int WBs = 68;
constexpr int WB_f = YB_f + 32 * YBs;             // [64][68]
constexpr int DG_f = WB_f + 64 * WBs;             // [32] deg
constexpr int WG_f = DG_f + 32;                   // [64] gate weights
constexpr int BB_f = WG_f + 64;                   // [64] bias
constexpr int EPI_BYTES = (BB_f + 64) * 4;        // 26880 B
constexpr int SMEM_BYTES = (EPI_BYTES > 16384) ? EPI_BYTES : 16384;

__device__ __forceinline__ unsigned short f2bf(float x) {
    union { float f; unsigned u; } v; v.f = x;
    unsigned r = v.u + 0x7FFFu + ((v.u >> 16) & 1u);   // RNE
    return (unsigned short)(r >> 16);
}

__global__ __launch_bounds__(512, 4)
void rfgcn_mfma(const float* __restrict__ X,      // [B][S][D]
                const int*   __restrict__ adj,    // [L][B][S][S]
                const float* __restrict__ nw,     // [B]
                const float* __restrict__ W_in,   // [L][D][D]
                const float* __restrict__ b_in,   // [L][D]
                const float* __restrict__ wg_in,  // [L][D]
                const float* __restrict__ bg_in,  // [L]
                const float* __restrict__ W_out,
                const float* __restrict__ b_out,
                const float* __restrict__ wg_out,
                const float* __restrict__ bg_out,
                float* __restrict__ out)
{
    __shared__ __align__(16) char smem[SMEM_BYTES];
    short* sm16 = (short*)smem;
    float* smf  = (float*)smem;

    const int tid  = threadIdx.x;
    const int b    = blockIdx.y;
    const int i0   = blockIdx.x * TI;
    const int w    = tid >> 6;       // wave 0..7
    const int lane = tid & 63;
    const int dir  = w & 1;          // 0 = in (A^T), 1 = out (A)
    const int wl   = w >> 1;         // label 0..3 owned by this wave
    const int lm   = lane & 15;
    const int lg   = lane >> 4;      // k-group 0..3

    f32x4 acc[2][4];                 // [row-tile rt][e-tile nt]
    f32x4 dacc[2];
#pragma unroll
    for (int rt = 0; rt < 2; ++rt) {
#pragma unroll
        for (int nt = 0; nt < 4; ++nt) acc[rt][nt] = (f32x4){0.f, 0.f, 0.f, 0.f};
        dacc[rt] = (f32x4){0.f, 0.f, 0.f, 0.f};
    }
    const short8 ones = {(short)0x3F80, (short)0x3F80, (short)0x3F80, (short)0x3F80,
                         (short)0x3F80, (short)0x3F80, (short)0x3F80, (short)0x3F80};

    const float* Xb = X + (size_t)b * Ssz * Dsz;
    const int*   Ab = adj + ((size_t)wl * Bsz + b) * Ssz * Ssz;   // this wave's label

    float xv[8];     // X prefetch (chunk t+1)
    int   aR[32];    // adjacency fragment prefetch: aR[rt*16+ks*8+j]

    // ---- per-wave adjacency fragment gather (no LDS) ----
#define ADJ_LOAD(T)                                                              \
    {                                                                            \
        const int J0 = (T) * TJ;                                                 \
        if (dir == 0) {                                                          \
            _Pragma("unroll")                                                    \
            for (int rt = 0; rt < 2; ++rt)                                       \
                _Pragma("unroll")                                                \
                for (int ks = 0; ks < 2; ++ks)                                   \
                    _Pragma("unroll")                                            \
                    for (int j = 0; j < 8; ++j)                                  \
                        aR[rt * 16 + ks * 8 + j] =                               \
                            Ab[(size_t)(J0 + 32 * ks + 8 * lg + j) * Ssz + i0 + 16 * rt + lm]; \
        } else {                                                                 \
            _Pragma("unroll")                                                    \
            for (int rt = 0; rt < 2; ++rt)                                       \
                _Pragma("unroll")                                                \
                for (int ks = 0; ks < 2; ++ks) {                                 \
                    const int* p = &Ab[(size_t)(i0 + 16 * rt + lm) * Ssz + J0 + 32 * ks + 8 * lg]; \
                    const int4 q0 = *(const int4*)p;                             \
                    const int4 q1 = *(const int4*)(p + 4);                       \
                    aR[rt * 16 + ks * 8 + 0] = q0.x; aR[rt * 16 + ks * 8 + 1] = q0.y; \
                    aR[rt * 16 + ks * 8 + 2] = q0.z; aR[rt * 16 + ks * 8 + 3] = q0.w; \
                    aR[rt * 16 + ks * 8 + 4] = q1.x; aR[rt * 16 + ks * 8 + 5] = q1.y; \
                    aR[rt * 16 + ks * 8 + 6] = q1.z; aR[rt * 16 + ks * 8 + 7] = q1.w; \
                }                                                                \
        }                                                                        \
    }

#define X_LOAD(T)                                                                \
    {                                                                            \
        const int J0 = (T) * TJ;                                                 \
        _Pragma("unroll")                                                        \
        for (int s = 0; s < 8; ++s) xv[s] = Xb[(size_t)(J0 + 8 * w + s) * Dsz + lane]; \
    }

#define X_WRITE(BUF)                                                             \
    {                                                                            \
        short8 hi;                                                               \
        _Pragma("unroll")                                                        \
        for (int s = 0; s < 8; ++s) hi[s] = (short)f2bf(xv[s]);                  \
        const int g = w ^ (lane & 7);                                            \
        *(short8*)(sm16 + XTb[BUF] + lane * 64 + g * 8) = hi;                    \
    }

    // ---- pipeline prologue
    X_LOAD(0)
    X_WRITE(0)          // waits X(0)
    ADJ_LOAD(0)         // in flight across the barrier
    X_LOAD(1)
    __syncthreads();    // buf0 visible

    for (int t = 0; t < 8; ++t) {
        const int cur = t & 1;

        // convert chunk t's adjacency fragments (waits adj(t), not X(t+1))
        short8 af[2][2];
#pragma unroll
        for (int rt = 0; rt < 2; ++rt)
#pragma unroll
            for (int ks = 0; ks < 2; ++ks)
#pragma unroll
                for (int j = 0; j < 8; ++j)
                    af[rt][ks][j] = aR[rt * 16 + ks * 8 + j] ? (short)0x3F80 : (short)0;

        if (t < 7) ADJ_LOAD(t + 1)          // refill aR, issue early
        if (t < 7) X_WRITE(cur ^ 1)         // chunk t+1 -> other buffer (reads of t-1 done at last bar)
        if (t < 6) X_LOAD(t + 2)

        // MFMA on buf[cur]
#pragma unroll
        for (int ks = 0; ks < 2; ++ks) {
            short8 bh[4];
#pragma unroll
            for (int nt = 0; nt < 4; ++nt) {
                const int d = nt * 16 + lm;
                const int g = (4 * ks + lg) ^ (d & 7);
                bh[nt] = *(const short8*)(sm16 + XTb[cur] + d * 64 + g * 8);
            }
#pragma unroll
            for (int rt = 0; rt < 2; ++rt) {
#pragma unroll
                for (int nt = 0; nt < 4; ++nt)
                    acc[rt][nt] = __builtin_amdgcn_mfma_f32_16x16x32_bf16(af[rt][ks], bh[nt], acc[rt][nt], 0, 0, 0);
                dacc[rt] = __builtin_amdgcn_mfma_f32_16x16x32_bf16(af[rt][ks], ones, dacc[rt], 0, 0, 0);
            }
        }
        __syncthreads();   // buf[cur] reads done; buf[cur^1] writes visible
    }
#undef ADJ_LOAD
#undef X_LOAD
#undef X_WRITE

    // ======== epilogue (r8-style): t = Y*W + deg*b; gate = Y*wg + deg*bg
    const int ei  = tid & 31;          // output row within tile
    const int ecg = tid >> 5;          // 4-column group 0..15
    float fin[4];
#pragma unroll
    for (int q = 0; q < 4; ++q) fin[q] = 0.f;

#pragma unroll
    for (int l = 0; l < Lsz; ++l) {
#pragma unroll
        for (int d2 = 0; d2 < 2; ++d2) {
            if (l + d2) __syncthreads();   // first pass covered by loop-final barrier
            if (dir == d2 && wl == l) {    // owning wave writes its full Y (32 rows)
#pragma unroll
                for (int rt = 0; rt < 2; ++rt)
#pragma unroll
                    for (int nt = 0; nt < 4; ++nt)
#pragma unroll
                        for (int r = 0; r < 4; ++r)
                            smf[YB_f + (16 * rt + 4 * lg + r) * YBs + nt * 16 + lm] = acc[rt][nt][r];
                if (lm == 0)
#pragma unroll
                    for (int rt = 0; rt < 2; ++rt)
#pragma unroll
                        for (int r = 0; r < 4; ++r)
                            smf[DG_f + 16 * rt + 4 * lg + r] = dacc[rt][r];
            }
            // stage W (all threads, coalesced float4)
            const float* Wp = (d2 ? W_out : W_in) + l * Dsz * Dsz;
            {
                const int r = tid >> 3, c8 = tid & 7;
                *(float4*)&smf[WB_f + r * WBs + 8 * c8]     = *(const float4*)&Wp[r * Dsz + 8 * c8];
                *(float4*)&smf[WB_f + r * WBs + 8 * c8 + 4] = *(const float4*)&Wp[r * Dsz + 8 * c8 + 4];
            }
            const float* wgp = (d2 ? wg_out : wg_in) + l * Dsz;
            const float* bp  = (d2 ? b_out  : b_in)  + l * Dsz;
            if (tid < 64)        smf[WG_f + tid]      = wgp[tid];
            else if (tid < 128)  smf[BB_f + tid - 64] = bp[tid - 64];
            const float bgs = (d2 ? bg_out : bg_in)[l];
            __syncthreads();

            const float dg = smf[DG_f + ei];
            float tq[4];
#pragma unroll
            for (int q = 0; q < 4; ++q) tq[q] = dg * smf[BB_f + 4 * ecg + q];
            float gate = dg * bgs;
#pragma unroll 4
            for (int e = 0; e < 64; ++e) {
                const float yv = smf[YB_f + ei * YBs + e];
                gate += yv * smf[WG_f + e];
#pragma unroll
                for (int q = 0; q < 4; ++q) tq[q] += yv * smf[WB_f + e * WBs + 4 * ecg + q];
            }
            const float sg = 1.f / (1.f + expf(-gate));
#pragma unroll
            for (int q = 0; q < 4; ++q) fin[q] += tq[q] * sg;
        }
    }

    const float inv = 1.f / (3.f * nw[b]);
    const float4 xr = *(const float4*)&Xb[(size_t)(i0 + ei) * Dsz + 4 * ecg];
    float4 o;
    o.x = (xr.x + fin[0]) * inv;
    o.y = (xr.y + fin[1]) * inv;
    o.z = (xr.z + fin[2]) * inv;
    o.w = (xr.w + fin[3]) * inv;
    *(float4*)(out + ((size_t)b * Ssz + i0 + ei) * Dsz + 4 * ecg) = o;
}

extern "C" void kernel_launch(void* const* d_in, const int* in_sizes, int n_in,
                              void* d_out, int out_size, void* d_ws, size_t ws_size,
                              hipStream_t stream)
{
    const float* X      = (const float*)d_in[0];
    const int*   adj    = (const int*)  d_in[1];
    const float* nw     = (const float*)d_in[2];
    const float* W_in   = (const float*)d_in[3];
    const float* b_in   = (const float*)d_in[4];
    const float* wg_in  = (const float*)d_in[5];
    const float* bg_in  = (const float*)d_in[6];
    const float* W_out  = (const float*)d_in[7];
    const float* b_out  = (const float*)d_in[8];
    const float* wg_out = (const float*)d_in[9];
    const float* bg_out = (const float*)d_in[10];
    float* out = (float*)d_out;

    dim3 grid(Ssz / TI, Bsz);   // (16, 32) = 512 blocks -> 2/CU
    dim3 block(512);
    hipLaunchKernelGGL(rfgcn_mfma, grid, block, 0, stream,
                       X, adj, nw, W_in, b_in, wg_in, bg_in,
                       W_out, b_out, wg_out, bg_out, out);
}

// Round 15
// 92.071 us; speedup vs baseline: 1.0750x; 1.0750x over previous
//
#include <hip/hip_runtime.h>
#include <math.h>

typedef short short8 __attribute__((ext_vector_type(8)));
typedef float f32x4  __attribute__((ext_vector_type(4)));

constexpr int Ssz = 512, Dsz = 64, Lsz = 4, Bsz = 32;
constexpr int TI = 32, TJ = 64;

// ---- workspace layout (10 MB) ----
constexpr size_t XBF_OFF = 0;                        // [B][64 d][512 s] bf16 = 2 MB
constexpr size_t RM_OFF  = 2u * 1024 * 1024;         // [L*B][8 jblk][512 i] u64 : bits of adj[i][j]  (dir=1)
constexpr size_t CM_OFF  = RM_OFF + 4u * 1024 * 1024;// [L*B][8 jblk][512 i] u64 : bits of adj[j][i]  (dir=0)
constexpr size_t WS_NEED = CM_OFF + 4u * 1024 * 1024;// 10 MB

// epilogue LDS overlay (floats)
constexpr int YBs = 69;                    // 69 == 5 mod 32 -> conflict-free
constexpr int YB_f = 0;                    // [32][69]
constexpr int WBs = 68;
constexpr int WB_f = YB_f + 32 * YBs;      // [64][68]
constexpr int DG_f = WB_f + 64 * WBs;      // [32]
constexpr int WG_f = DG_f + 32;            // [64]
constexpr int BB_f = WG_f + 64;            // [64]
constexpr int EPI_FLOATS = BB_f + 64;      // 6720 floats = 26880 B

__device__ __forceinline__ unsigned short f2bf(float x) {
    union { float f; unsigned u; } v; v.f = x;
    unsigned r = v.u + 0x7FFFu + ((v.u >> 16) & 1u);   // RNE
    return (unsigned short)(r >> 16);
}

// ============ P1: X [B][S][D] f32 -> Xbf^T [B][D][S] bf16 ============
__global__ __launch_bounds__(256)
void xpose_kernel(const float* __restrict__ X, unsigned short* __restrict__ xbf)
{
    __shared__ unsigned short t[64][66];
    const int b = blockIdx.y, s0 = blockIdx.x * 64;
    const int tid = threadIdx.x;
    const int c = tid & 63, r4 = tid >> 6;
    const float* Xb = X + (size_t)b * Ssz * Dsz;
#pragma unroll
    for (int k = 0; k < 16; ++k) {
        const int s = r4 + 4 * k;
        t[s][c] = f2bf(Xb[(size_t)(s0 + s) * Dsz + c]);   // coalesced read
    }
    __syncthreads();
    unsigned short* o = xbf + (size_t)b * Dsz * Ssz;
#pragma unroll
    for (int k = 0; k < 16; ++k) {
        const int d = r4 + 4 * k;
        o[(size_t)d * Ssz + s0 + c] = t[c][d];            // coalesced write
    }
}

// ============ P2: adjacency -> row/col bitmasks (one streaming sweep) ============
__global__ __launch_bounds__(256)
void mask_kernel(const int* __restrict__ adj,
                 unsigned long long* __restrict__ rm,
                 unsigned long long* __restrict__ cm)
{
    const int tid  = threadIdx.x;
    const int lane = tid & 63;
    const int wt   = blockIdx.x * 4 + (tid >> 6);   // wave-tile 0..8191
    const int lb   = wt >> 6;                       // (l*B + b)
    const int rem  = wt & 63;
    const int r1t  = (rem >> 3) * 64;               // first-index tile base
    const int r2t  = (rem & 7) * 64;                // second-index tile base
    const int* A = adj + (size_t)lb * Ssz * Ssz;

    unsigned long long c = 0ull, rmine = 0ull;
#pragma unroll 4
    for (int j = 0; j < 64; ++j) {
        const int a = A[(size_t)(r1t + j) * Ssz + r2t + lane];   // coalesced 256B/wave
        const unsigned long long bal = __ballot(a != 0);          // bits over r2 (fixed r1t+j)
        if (lane == j) rmine = bal;
        c |= ((unsigned long long)(a != 0)) << j;                 // bits over r1 (fixed r2=lane)
    }
    // rm entry (first-index row, bits over second index) -> dir=1 (adj[i][j])
    rm[((size_t)lb * 8 + (r2t >> 6)) * 512 + r1t + lane] = rmine;
    // cm entry (second-index row, bits over first index) -> dir=0 (adj[j][i])
    cm[((size_t)lb * 8 + (r1t >> 6)) * 512 + r2t + lane] = c;
}

// ============ main: barrier-free MFMA aggregation + r8 epilogue ============
__global__ __launch_bounds__(512, 2)
void rfgcn_main(const float* __restrict__ X,
                const unsigned short* __restrict__ xbf,
                const unsigned long long* __restrict__ rm,
                const unsigned long long* __restrict__ cm,
                const float* __restrict__ nw,
                const float* __restrict__ W_in,  const float* __restrict__ b_in,
                const float* __restrict__ wg_in, const float* __restrict__ bg_in,
                const float* __restrict__ W_out, const float* __restrict__ b_out,
                const float* __restrict__ wg_out,const float* __restrict__ bg_out,
                float* __restrict__ out)
{
    __shared__ float smf[EPI_FLOATS];

    const int tid  = threadIdx.x;
    const int b    = blockIdx.y;
    const int i0   = blockIdx.x * TI;
    const int w    = tid >> 6;
    const int lane = tid & 63;
    const int dir  = w & 1;          // 0 = in (adj[j][i]) -> cm ; 1 = out (adj[i][j]) -> rm
    const int wl   = w >> 1;         // label
    const int lm   = lane & 15;
    const int lg   = lane >> 4;

    f32x4 acc[2][4];
    f32x4 dacc[2];
#pragma unroll
    for (int rt = 0; rt < 2; ++rt) {
#pragma unroll
        for (int nt = 0; nt < 4; ++nt) acc[rt][nt] = (f32x4){0.f, 0.f, 0.f, 0.f};
        dacc[rt] = (f32x4){0.f, 0.f, 0.f, 0.f};
    }
    const short8 ones = {(short)0x3F80, (short)0x3F80, (short)0x3F80, (short)0x3F80,
                         (short)0x3F80, (short)0x3F80, (short)0x3F80, (short)0x3F80};

    const unsigned long long* Mb = (dir ? rm : cm) + (size_t)(wl * Bsz + b) * 8 * 512;
    const unsigned short* xp0 = xbf + (size_t)b * Dsz * Ssz;

    for (int jc = 0; jc < 8; ++jc) {
        const unsigned long long m0 = Mb[(size_t)jc * 512 + i0 + lm];
        const unsigned long long m1 = Mb[(size_t)jc * 512 + i0 + 16 + lm];
        const unsigned short* xp = xp0 + jc * 64;
#pragma unroll
        for (int ks = 0; ks < 2; ++ks) {
            short8 bh[4];
#pragma unroll
            for (int nt = 0; nt < 4; ++nt)
                bh[nt] = *(const short8*)(xp + (size_t)(16 * nt + lm) * Ssz + 8 * (4 * ks + lg));
#pragma unroll
            for (int rt = 0; rt < 2; ++rt) {
                const unsigned bytev = (unsigned)((rt ? m1 : m0) >> (32 * ks + 8 * lg)) & 0xFFu;
                short8 af;
#pragma unroll
                for (int jj = 0; jj < 8; ++jj)
                    af[jj] = ((bytev >> jj) & 1u) ? (short)0x3F80 : (short)0;
#pragma unroll
                for (int nt = 0; nt < 4; ++nt)
                    acc[rt][nt] = __builtin_amdgcn_mfma_f32_16x16x32_bf16(af, bh[nt], acc[rt][nt], 0, 0, 0);
                dacc[rt] = __builtin_amdgcn_mfma_f32_16x16x32_bf16(af, ones, dacc[rt], 0, 0, 0);
            }
        }
    }

    // ======== epilogue (r12-verified): t = Y*W + deg*b; gate = Y*wg + deg*bg
    const int ei  = tid & 31;
    const int ecg = tid >> 5;
    float fin[4];
#pragma unroll
    for (int q = 0; q < 4; ++q) fin[q] = 0.f;

#pragma unroll
    for (int l = 0; l < Lsz; ++l) {
#pragma unroll
        for (int d2 = 0; d2 < 2; ++d2) {
            __syncthreads();   // waves may be de-phased (no main-loop barriers)
            if (dir == d2 && wl == l) {
#pragma unroll
                for (int rt = 0; rt < 2; ++rt)
#pragma unroll
                    for (int nt = 0; nt < 4; ++nt)
#pragma unroll
                        for (int r = 0; r < 4; ++r)
                            smf[YB_f + (16 * rt + 4 * lg + r) * YBs + nt * 16 + lm] = acc[rt][nt][r];
                if (lm == 0)
#pragma unroll
                    for (int rt = 0; rt < 2; ++rt)
#pragma unroll
                        for (int r = 0; r < 4; ++r)
                            smf[DG_f + 16 * rt + 4 * lg + r] = dacc[rt][r];
            }
            const float* Wp = (d2 ? W_out : W_in) + l * Dsz * Dsz;
            {
                const int r = tid >> 3, c8 = tid & 7;
                *(float4*)&smf[WB_f + r * WBs + 8 * c8]     = *(const float4*)&Wp[r * Dsz + 8 * c8];
                *(float4*)&smf[WB_f + r * WBs + 8 * c8 + 4] = *(const float4*)&Wp[r * Dsz + 8 * c8 + 4];
            }
            const float* wgp = (d2 ? wg_out : wg_in) + l * Dsz;
            const float* bp  = (d2 ? b_out  : b_in)  + l * Dsz;
            if (tid < 64)        smf[WG_f + tid]      = wgp[tid];
            else if (tid < 128)  smf[BB_f + tid - 64] = bp[tid - 64];
            const float bgs = (d2 ? bg_out : bg_in)[l];
            __syncthreads();

            const float dg = smf[DG_f + ei];
            float tq[4];
#pragma unroll
            for (int q = 0; q < 4; ++q) tq[q] = dg * smf[BB_f + 4 * ecg + q];
            float gate = dg * bgs;
#pragma unroll 4
            for (int e = 0; e < 64; ++e) {
                const float yv = smf[YB_f + ei * YBs + e];
                gate += yv * smf[WG_f + e];
#pragma unroll
                for (int q = 0; q < 4; ++q) tq[q] += yv * smf[WB_f + e * WBs + 4 * ecg + q];
            }
            const float sg = 1.f / (1.f + expf(-gate));
#pragma unroll
            for (int q = 0; q < 4; ++q) fin[q] += tq[q] * sg;
        }
    }

    const float inv = 1.f / (3.f * nw[b]);
    const float* Xb = X + (size_t)b * Ssz * Dsz;
    const float4 xr = *(const float4*)&Xb[(size_t)(i0 + ei) * Dsz + 4 * ecg];
    float4 o;
    o.x = (xr.x + fin[0]) * inv;
    o.y = (xr.y + fin[1]) * inv;
    o.z = (xr.z + fin[2]) * inv;
    o.w = (xr.w + fin[3]) * inv;
    *(float4*)(out + ((size_t)b * Ssz + i0 + ei) * Dsz + 4 * ecg) = o;
}

// ============ fallback (r12 kernel, 76 us verified) — used if ws too small ============
constexpr int XTb[2] = {0, 4096};
constexpr int FB_SMEM = EPI_FLOATS * 4;

__global__ __launch_bounds__(512, 4)
void rfgcn_fallback(const float* __restrict__ X, const int* __restrict__ adj,
                    const float* __restrict__ nw,
                    const float* __restrict__ W_in,  const float* __restrict__ b_in,
                    const float* __restrict__ wg_in, const float* __restrict__ bg_in,
                    const float* __restrict__ W_out, const float* __restrict__ b_out,
                    const float* __restrict__ wg_out,const float* __restrict__ bg_out,
                    float* __restrict__ out)
{
    __shared__ __align__(16) char smem[FB_SMEM];
    short* sm16 = (short*)smem;
    float* smf  = (float*)smem;

    const int tid  = threadIdx.x;
    const int b    = blockIdx.y;
    const int i0   = blockIdx.x * TI;
    const int w    = tid >> 6;
    const int lane = tid & 63;
    const int dir  = w & 1;
    const int wl   = w >> 1;
    const int lm   = lane & 15;
    const int lg   = lane >> 4;

    f32x4 acc[2][4];
    f32x4 dacc[2];
#pragma unroll
    for (int rt = 0; rt < 2; ++rt) {
#pragma unroll
        for (int nt = 0; nt < 4; ++nt) acc[rt][nt] = (f32x4){0.f, 0.f, 0.f, 0.f};
        dacc[rt] = (f32x4){0.f, 0.f, 0.f, 0.f};
    }
    const short8 ones = {(short)0x3F80, (short)0x3F80, (short)0x3F80, (short)0x3F80,
                         (short)0x3F80, (short)0x3F80, (short)0x3F80, (short)0x3F80};

    const float* Xb = X + (size_t)b * Ssz * Dsz;
    const int*   Ab = adj + ((size_t)wl * Bsz + b) * Ssz * Ssz;

    float xv[8];
    int   aR[32];

#define ADJ_LOAD(T)                                                              \
    {                                                                            \
        const int J0 = (T) * TJ;                                                 \
        if (dir == 0) {                                                          \
            _Pragma("unroll")                                                    \
            for (int rt = 0; rt < 2; ++rt)                                       \
                _Pragma("unroll")                                                \
                for (int ks = 0; ks < 2; ++ks)                                   \
                    _Pragma("unroll")                                            \
                    for (int j = 0; j < 8; ++j)                                  \
                        aR[rt * 16 + ks * 8 + j] =                               \
                            Ab[(size_t)(J0 + 32 * ks + 8 * lg + j) * Ssz + i0 + 16 * rt + lm]; \
        } else {                                                                 \
            _Pragma("unroll")                                                    \
            for (int rt = 0; rt < 2; ++rt)                                       \
                _Pragma("unroll")                                                \
                for (int ks = 0; ks < 2; ++ks) {                                 \
                    const int* p = &Ab[(size_t)(i0 + 16 * rt + lm) * Ssz + J0 + 32 * ks + 8 * lg]; \
                    const int4 q0 = *(const int4*)p;                             \
                    const int4 q1 = *(const int4*)(p + 4);                       \
                    aR[rt * 16 + ks * 8 + 0] = q0.x; aR[rt * 16 + ks * 8 + 1] = q0.y; \
                    aR[rt * 16 + ks * 8 + 2] = q0.z; aR[rt * 16 + ks * 8 + 3] = q0.w; \
                    aR[rt * 16 + ks * 8 + 4] = q1.x; aR[rt * 16 + ks * 8 + 5] = q1.y; \
                    aR[rt * 16 + ks * 8 + 6] = q1.z; aR[rt * 16 + ks * 8 + 7] = q1.w; \
                }                                                                \
        }                                                                        \
    }
#define X_LOAD(T)                                                                \
    {                                                                            \
        const int J0 = (T) * TJ;                                                 \
        _Pragma("unroll")                                                        \
        for (int s = 0; s < 8; ++s) xv[s] = Xb[(size_t)(J0 + 8 * w + s) * Dsz + lane]; \
    }
#define X_WRITE(BUF)                                                             \
    {                                                                            \
        short8 hi;                                                               \
        _Pragma("unroll")                                                        \
        for (int s = 0; s < 8; ++s) hi[s] = (short)f2bf(xv[s]);                  \
        const int g = w ^ (lane & 7);                                            \
        *(short8*)(sm16 + XTb[BUF] + lane * 64 + g * 8) = hi;                    \
    }

    X_LOAD(0)
    X_WRITE(0)
    ADJ_LOAD(0)
    X_LOAD(1)
    __syncthreads();

    for (int t = 0; t < 8; ++t) {
        const int cur = t & 1;
        short8 af[2][2];
#pragma unroll
        for (int rt = 0; rt < 2; ++rt)
#pragma unroll
            for (int ks = 0; ks < 2; ++ks)
#pragma unroll
                for (int j = 0; j < 8; ++j)
                    af[rt][ks][j] = aR[rt * 16 + ks * 8 + j] ? (short)0x3F80 : (short)0;

        if (t < 7) ADJ_LOAD(t + 1)
        if (t < 7) X_WRITE(cur ^ 1)
        if (t < 6) X_LOAD(t + 2)

#pragma unroll
        for (int ks = 0; ks < 2; ++ks) {
            short8 bh[4];
#pragma unroll
            for (int nt = 0; nt < 4; ++nt) {
                const int d = nt * 16 + lm;
                const int g = (4 * ks + lg) ^ (d & 7);
                bh[nt] = *(const short8*)(sm16 + XTb[cur] + d * 64 + g * 8);
            }
#pragma unroll
            for (int rt = 0; rt < 2; ++rt) {
#pragma unroll
                for (int nt = 0; nt < 4; ++nt)
                    acc[rt][nt] = __builtin_amdgcn_mfma_f32_16x16x32_bf16(af[rt][ks], bh[nt], acc[rt][nt], 0, 0, 0);
                dacc[rt] = __builtin_amdgcn_mfma_f32_16x16x32_bf16(af[rt][ks], ones, dacc[rt], 0, 0, 0);
            }
        }
        __syncthreads();
    }
#undef ADJ_LOAD
#undef X_LOAD
#undef X_WRITE

    const int ei  = tid & 31;
    const int ecg = tid >> 5;
    float fin[4];
#pragma unroll
    for (int q = 0; q < 4; ++q) fin[q] = 0.f;

#pragma unroll
    for (int l = 0; l < Lsz; ++l) {
#pragma unroll
        for (int d2 = 0; d2 < 2; ++d2) {
            if (l + d2) __syncthreads();
            if (dir == d2 && wl == l) {
#pragma unroll
                for (int rt = 0; rt < 2; ++rt)
#pragma unroll
                    for (int nt = 0; nt < 4; ++nt)
#pragma unroll
                        for (int r = 0; r < 4; ++r)
                            smf[YB_f + (16 * rt + 4 * lg + r) * YBs + nt * 16 + lm] = acc[rt][nt][r];
                if (lm == 0)
#pragma unroll
                    for (int rt = 0; rt < 2; ++rt)
#pragma unroll
                        for (int r = 0; r < 4; ++r)
                            smf[DG_f + 16 * rt + 4 * lg + r] = dacc[rt][r];
            }
            const float* Wp = (d2 ? W_out : W_in) + l * Dsz * Dsz;
            {
                const int r = tid >> 3, c8 = tid & 7;
                *(float4*)&smf[WB_f + r * WBs + 8 * c8]     = *(const float4*)&Wp[r * Dsz + 8 * c8];
                *(float4*)&smf[WB_f + r * WBs + 8 * c8 + 4] = *(const float4*)&Wp[r * Dsz + 8 * c8 + 4];
            }
            const float* wgp = (d2 ? wg_out : wg_in) + l * Dsz;
            const float* bp  = (d2 ? b_out  : b_in)  + l * Dsz;
            if (tid < 64)        smf[WG_f + tid]      = wgp[tid];
            else if (tid < 128)  smf[BB_f + tid - 64] = bp[tid - 64];
            const float bgs = (d2 ? bg_out : bg_in)[l];
            __syncthreads();

            const float dg = smf[DG_f + ei];
            float tq[4];
#pragma unroll
            for (int q = 0; q < 4; ++q) tq[q] = dg * smf[BB_f + 4 * ecg + q];
            float gate = dg * bgs;
#pragma unroll 4
            for (int e = 0; e < 64; ++e) {
                const float yv = smf[YB_f + ei * YBs + e];
                gate += yv * smf[WG_f + e];
#pragma unroll
                for (int q = 0; q < 4; ++q) tq[q] += yv * smf[WB_f + e * WBs + 4 * ecg + q];
            }
            const float sg = 1.f / (1.f + expf(-gate));
#pragma unroll
            for (int q = 0; q < 4; ++q) fin[q] += tq[q] * sg;
        }
    }

    const float inv = 1.f / (3.f * nw[b]);
    const float4 xr = *(const float4*)&Xb[(size_t)(i0 + ei) * Dsz + 4 * ecg];
    float4 o;
    o.x = (xr.x + fin[0]) * inv;
    o.y = (xr.y + fin[1]) * inv;
    o.z = (xr.z + fin[2]) * inv;
    o.w = (xr.w + fin[3]) * inv;
    *(float4*)(out + ((size_t)b * Ssz + i0 + ei) * Dsz + 4 * ecg) = o;
}

extern "C" void kernel_launch(void* const* d_in, const int* in_sizes, int n_in,
                              void* d_out, int out_size, void* d_ws, size_t ws_size,
                              hipStream_t stream)
{
    const float* X      = (const float*)d_in[0];
    const int*   adj    = (const int*)  d_in[1];
    const float* nw     = (const float*)d_in[2];
    const float* W_in   = (const float*)d_in[3];
    const float* b_in   = (const float*)d_in[4];
    const float* wg_in  = (const float*)d_in[5];
    const float* bg_in  = (const float*)d_in[6];
    const float* W_out  = (const float*)d_in[7];
    const float* b_out  = (const float*)d_in[8];
    const float* wg_out = (const float*)d_in[9];
    const float* bg_out = (const float*)d_in[10];
    float* out = (float*)d_out;

    if (ws_size >= WS_NEED) {
        unsigned short*      xbf = (unsigned short*)((char*)d_ws + XBF_OFF);
        unsigned long long*  rmp = (unsigned long long*)((char*)d_ws + RM_OFF);
        unsigned long long*  cmp = (unsigned long long*)((char*)d_ws + CM_OFF);
        hipLaunchKernelGGL(xpose_kernel, dim3(8, 32), dim3(256), 0, stream, X, xbf);
        hipLaunchKernelGGL(mask_kernel, dim3(2048), dim3(256), 0, stream, adj, rmp, cmp);
        hipLaunchKernelGGL(rfgcn_main, dim3(Ssz / TI, Bsz), dim3(512), 0, stream,
                           X, xbf, rmp, cmp, nw, W_in, b_in, wg_in, bg_in,
                           W_out, b_out, wg_out, bg_out, out);
    } else {
        hipLaunchKernelGGL(rfgcn_fallback, dim3(Ssz / TI, Bsz), dim3(512), 0, stream,
                           X, adj, nw, W_in, b_in, wg_in, bg_in,
                           W_out, b_out, wg_out, bg_out, out);
    }
}